// Round 2
// baseline (2346.836 us; speedup 1.0000x reference)
//
#include <hip/hip_runtime.h>

#define NS_TOT 2000
#define NA 1000
#define NI 5
#define NH 32

// tanh(x) = 1 - 2/(exp(2x)+1); exp -> v_exp_f32, rcp -> v_rcp_f32.
// Saturates correctly for |x| large (exp->inf => 1, exp->0 => -1). ~1e-6 abs err.
__device__ __forceinline__ float fast_tanh(float x) {
    float E = __expf(2.0f * x);                 // v_mul + v_exp_f32
    float r = __builtin_amdgcn_rcpf(E + 1.0f);  // v_add + v_rcp_f32
    return fmaf(-2.0f, r, 1.0f);
}

// acc[4q..4q+3] += xval * wv  (inline fn, not macro: macro param named `x`
// collided with the float4 `.x` member access in R0)
__device__ __forceinline__ void fma4(float* acc, int q, float xval, float4 wv) {
    acc[4*q+0] = fmaf(xval, wv.x, acc[4*q+0]);
    acc[4*q+1] = fmaf(xval, wv.y, acc[4*q+1]);
    acc[4*q+2] = fmaf(xval, wv.z, acc[4*q+2]);
    acc[4*q+3] = fmaf(xval, wv.w, acc[4*q+3]);
}

__global__ __launch_bounds__(256, 2) void mlp_per_atom(
    const float* __restrict__ g,
    const float* __restrict__ W1, const float* __restrict__ b1,
    const float* __restrict__ W2, const float* __restrict__ b2,
    const float* __restrict__ W3, const float* __restrict__ b3,
    float* __restrict__ out)
{
    const int a = blockIdx.x;   // one block per atom: weights staged once in LDS
    const int t = threadIdx.x;

    __shared__ __align__(16) float sW1[NI * NH];
    __shared__ __align__(16) float sB1[NH];
    __shared__ __align__(16) float sW2[NH * NH];
    __shared__ __align__(16) float sB2[NH];
    __shared__ __align__(16) float sW3[NH];
    __shared__ float sB3;

    for (int i = t; i < NI * NH; i += 256) sW1[i] = W1[a * NI * NH + i];
    for (int i = t; i < NH * NH; i += 256) sW2[i] = W2[a * NH * NH + i];
    if (t < NH) {
        sB1[t] = b1[a * NH + t];
        sB2[t] = b2[a * NH + t];
        sW3[t] = W3[a * NH + t];
    }
    if (t == 0) sB3 = b3[a];
    __syncthreads();

    const float4* w1v = (const float4*)sW1;
    const float4* b1v = (const float4*)sB1;
    const float4* w2v = (const float4*)sW2;
    const float4* b2v = (const float4*)sB2;
    const float4* w3v = (const float4*)sW3;
    const float bias3 = sB3;

    // Each thread handles 2 structs per iteration: every ds_read_b128
    // of 4 weights feeds 8 FMAs -> VALU-bound, not LDS-bound.
    for (int s0 = t; s0 < NS_TOT; s0 += 512) {
        const int s1 = s0 + 256;
        const bool v1 = (s1 < NS_TOT);
        const int s1c = v1 ? s1 : s0;   // clamp: duplicate work, store skipped

        const float* gp0 = g + ((size_t)s0 * NA + a) * NI;
        const float* gp1 = g + ((size_t)s1c * NA + a) * NI;
        float g0[NI], g1[NI];
        #pragma unroll
        for (int i = 0; i < NI; ++i) { g0[i] = gp0[i]; g1[i] = gp1[i]; }

        // ---- layer 1: 5 -> 32 ----
        float h0[NH], h1[NH];
        #pragma unroll
        for (int q = 0; q < NH / 4; ++q) {
            float4 b = b1v[q];
            h0[4*q+0] = b.x; h0[4*q+1] = b.y; h0[4*q+2] = b.z; h0[4*q+3] = b.w;
            h1[4*q+0] = b.x; h1[4*q+1] = b.y; h1[4*q+2] = b.z; h1[4*q+3] = b.w;
        }
        #pragma unroll
        for (int i = 0; i < NI; ++i) {
            const float x0 = g0[i], x1 = g1[i];
            #pragma unroll
            for (int q = 0; q < NH / 4; ++q) {
                float4 w = w1v[i * (NH / 4) + q];
                fma4(h0, q, x0, w);
                fma4(h1, q, x1, w);
            }
        }
        #pragma unroll
        for (int j = 0; j < NH; ++j) { h0[j] = fast_tanh(h0[j]); h1[j] = fast_tanh(h1[j]); }

        // ---- layer 2: 32 -> 32 (the 2048-FLOP core) ----
        float c0[NH], c1[NH];
        #pragma unroll
        for (int q = 0; q < NH / 4; ++q) {
            float4 b = b2v[q];
            c0[4*q+0] = b.x; c0[4*q+1] = b.y; c0[4*q+2] = b.z; c0[4*q+3] = b.w;
            c1[4*q+0] = b.x; c1[4*q+1] = b.y; c1[4*q+2] = b.z; c1[4*q+3] = b.w;
        }
        #pragma unroll
        for (int k = 0; k < NH; ++k) {
            const float x0 = h0[k], x1 = h1[k];
            #pragma unroll
            for (int q = 0; q < NH / 4; ++q) {
                float4 w = w2v[k * (NH / 4) + q];
                fma4(c0, q, x0, w);
                fma4(c1, q, x1, w);
            }
        }
        #pragma unroll
        for (int j = 0; j < NH; ++j) { c0[j] = fast_tanh(c0[j]); c1[j] = fast_tanh(c1[j]); }

        // ---- layer 3: 32 -> 1 ----
        float e0 = bias3, e1 = bias3;
        #pragma unroll
        for (int q = 0; q < NH / 4; ++q) {
            float4 w = w3v[q];
            e0 = fmaf(c0[4*q+0], w.x, e0);
            e0 = fmaf(c0[4*q+1], w.y, e0);
            e0 = fmaf(c0[4*q+2], w.z, e0);
            e0 = fmaf(c0[4*q+3], w.w, e0);
            e1 = fmaf(c1[4*q+0], w.x, e1);
            e1 = fmaf(c1[4*q+1], w.y, e1);
            e1 = fmaf(c1[4*q+2], w.z, e1);
            e1 = fmaf(c1[4*q+3], w.w, e1);
        }

        out[(size_t)s0 * NA + a] = e0;
        if (v1) out[(size_t)s1 * NA + a] = e1;
    }
}

extern "C" void kernel_launch(void* const* d_in, const int* in_sizes, int n_in,
                              void* d_out, int out_size, void* d_ws, size_t ws_size,
                              hipStream_t stream) {
    const float* g  = (const float*)d_in[0];
    const float* W1 = (const float*)d_in[1];
    const float* b1 = (const float*)d_in[2];
    const float* W2 = (const float*)d_in[3];
    const float* b2 = (const float*)d_in[4];
    const float* W3 = (const float*)d_in[5];
    const float* b3 = (const float*)d_in[6];
    float* out = (float*)d_out;
    mlp_per_atom<<<dim3(NA), dim3(256), 0, stream>>>(g, W1, b1, W2, b2, W3, b3, out);
}

// Round 3
// 543.692 us; speedup vs baseline: 4.3165x; 4.3165x over previous
//
#include <hip/hip_runtime.h>

#define NS_TOT 2000
#define NA 1000
#define NI 5
#define NH 32

// tanh(x) = 1 - 2/(exp(2x)+1); exp -> v_exp_f32, rcp -> v_rcp_f32.
// Saturates correctly for |x| large. ~1e-6 abs err.
__device__ __forceinline__ float fast_tanh(float x) {
    float E = __expf(2.0f * x);
    float r = __builtin_amdgcn_rcpf(E + 1.0f);
    return fmaf(-2.0f, r, 1.0f);
}

__device__ __forceinline__ void fma4(float* acc, int q, float xval, float4 wv) {
    acc[4*q+0] = fmaf(xval, wv.x, acc[4*q+0]);
    acc[4*q+1] = fmaf(xval, wv.y, acc[4*q+1]);
    acc[4*q+2] = fmaf(xval, wv.z, acc[4*q+2]);
    acc[4*q+3] = fmaf(xval, wv.w, acc[4*q+3]);
}

// NS=1 per thread: peak live floats = h[32]+c[32]+temps ~ 90 VGPR -> no spill
// at the 128-VGPR cap implied by __launch_bounds__(256,4). R2's NS=2 needed
// ~170 live VGPRs, spilled, and drove 6.6 GB of HBM scratch traffic.
__global__ __launch_bounds__(256, 4) void mlp_per_atom(
    const float* __restrict__ g,
    const float* __restrict__ W1, const float* __restrict__ b1,
    const float* __restrict__ W2, const float* __restrict__ b2,
    const float* __restrict__ W3, const float* __restrict__ b3,
    float* __restrict__ out)
{
    const int a = blockIdx.x;   // one block per atom: weights staged once in LDS
    const int t = threadIdx.x;

    __shared__ __align__(16) float sW1[NI * NH];
    __shared__ __align__(16) float sB1[NH];
    __shared__ __align__(16) float sW2[NH * NH];
    __shared__ __align__(16) float sB2[NH];
    __shared__ __align__(16) float sW3[NH];
    __shared__ float sB3;

    for (int i = t; i < NI * NH; i += 256) sW1[i] = W1[a * NI * NH + i];
    for (int i = t; i < NH * NH; i += 256) sW2[i] = W2[a * NH * NH + i];
    if (t < NH) {
        sB1[t] = b1[a * NH + t];
        sB2[t] = b2[a * NH + t];
        sW3[t] = W3[a * NH + t];
    }
    if (t == 0) sB3 = b3[a];
    __syncthreads();

    const float4* w1v = (const float4*)sW1;
    const float4* b1v = (const float4*)sB1;
    const float4* w2v = (const float4*)sW2;
    const float4* b2v = (const float4*)sB2;
    const float4* w3v = (const float4*)sW3;
    const float bias3 = sB3;

    for (int s = t; s < NS_TOT; s += 256) {
        const float* gp = g + ((size_t)s * NA + a) * NI;
        float gv[NI];
        #pragma unroll
        for (int i = 0; i < NI; ++i) gv[i] = gp[i];

        // ---- layer 1: 5 -> 32 ----
        float h[NH];
        #pragma unroll
        for (int q = 0; q < NH / 4; ++q) {
            float4 b = b1v[q];
            h[4*q+0] = b.x; h[4*q+1] = b.y; h[4*q+2] = b.z; h[4*q+3] = b.w;
        }
        #pragma unroll
        for (int i = 0; i < NI; ++i) {
            const float x0 = gv[i];
            #pragma unroll
            for (int q = 0; q < NH / 4; ++q)
                fma4(h, q, x0, w1v[i * (NH / 4) + q]);
        }
        #pragma unroll
        for (int j = 0; j < NH; ++j) h[j] = fast_tanh(h[j]);

        // ---- layer 2: 32 -> 32 (the 2048-FLOP core) ----
        float c[NH];
        #pragma unroll
        for (int q = 0; q < NH / 4; ++q) {
            float4 b = b2v[q];
            c[4*q+0] = b.x; c[4*q+1] = b.y; c[4*q+2] = b.z; c[4*q+3] = b.w;
        }
        #pragma unroll
        for (int k = 0; k < NH; ++k) {
            const float x0 = h[k];
            #pragma unroll
            for (int q = 0; q < NH / 4; ++q)
                fma4(c, q, x0, w2v[k * (NH / 4) + q]);
        }
        #pragma unroll
        for (int j = 0; j < NH; ++j) c[j] = fast_tanh(c[j]);

        // ---- layer 3: 32 -> 1 ----
        float e = bias3;
        #pragma unroll
        for (int q = 0; q < NH / 4; ++q) {
            float4 w = w3v[q];
            e = fmaf(c[4*q+0], w.x, e);
            e = fmaf(c[4*q+1], w.y, e);
            e = fmaf(c[4*q+2], w.z, e);
            e = fmaf(c[4*q+3], w.w, e);
        }

        out[(size_t)s * NA + a] = e;
    }
}

extern "C" void kernel_launch(void* const* d_in, const int* in_sizes, int n_in,
                              void* d_out, int out_size, void* d_ws, size_t ws_size,
                              hipStream_t stream) {
    const float* g  = (const float*)d_in[0];
    const float* W1 = (const float*)d_in[1];
    const float* b1 = (const float*)d_in[2];
    const float* W2 = (const float*)d_in[3];
    const float* b2 = (const float*)d_in[4];
    const float* W3 = (const float*)d_in[5];
    const float* b3 = (const float*)d_in[6];
    float* out = (float*)d_out;
    mlp_per_atom<<<dim3(NA), dim3(256), 0, stream>>>(g, W1, b1, W2, b2, W3, b3, out);
}